// Round 13
// baseline (634.731 us; speedup 1.0000x reference)
//
#include <hip/hip_runtime.h>
#include <hip/hip_bf16.h>

#define EPS_BN 1e-5f

constexpr int B  = 2048, F0 = 64, K = 14;
constexpr int C1 = 64,  F1 = 32;
constexpr int C2 = 128, F2 = 16;
constexpr int C3 = 256, F3 = 8;

typedef __attribute__((ext_vector_type(8))) short bf16x8;
typedef __attribute__((ext_vector_type(4))) float f32x4;

__device__ __forceinline__ float bf2f(unsigned short u) {
    union { unsigned int i; float f; } x; x.i = ((unsigned int)u) << 16; return x.f;
}
__device__ __forceinline__ unsigned short f2bf(float f) {
    union { float f; unsigned int i; } x; x.f = f;
    unsigned int r = (x.i + 0x7fffu + ((x.i >> 16) & 1u)) >> 16;
    return (unsigned short)r;
}

// async global->LDS 16B copy. HW: LDS dest = wave-uniform base + lane*16.
// Callers must keep whole waves active with per-lane-consecutive dests.
__device__ __forceinline__ void gl_lds16(const void* g, void* l) {
    __builtin_amdgcn_global_load_lds(
        (const __attribute__((address_space(1))) unsigned int*)g,
        (__attribute__((address_space(3))) unsigned int*)l,
        16, 0, 0);
}

// ---- fold BN into conv1 weights; also zero the 16B pad-source block ----
__global__ void repack_w1(const float* __restrict__ w1, const float* __restrict__ g,
                          const float* __restrict__ bb, const float* __restrict__ m,
                          const float* __restrict__ v, float* __restrict__ w1f,
                          float* __restrict__ t1, float* __restrict__ zbuf) {
    int i = blockIdx.x * 256 + threadIdx.x;
    if (i < 4) zbuf[i] = 0.0f;
    if (i < C1) {
        float s = g[i] * rsqrtf(v[i] + EPS_BN);
        t1[i] = bb[i] - m[i] * s;
    }
    if (i < C1 * 2 * 9) {
        int c = i / 18;
        float s = g[c] * rsqrtf(v[c] + EPS_BN);
        w1f[i] = w1[i] * s;
    }
}

// ---- repack conv weights into MFMA B-fragment layout, bf16, BN-folded ----
// wp[((chunk*COUT + n)*32) + kk] = W[tap][ci][n]*s[n], chunk=tap*(CIN/32)+cc, ci=cc*32+kk
template<int CIN, int COUT>
__global__ void repack_mfma(const float* __restrict__ w, const float* __restrict__ g,
                            const float* __restrict__ bb, const float* __restrict__ m,
                            const float* __restrict__ v, unsigned short* __restrict__ wp,
                            float* __restrict__ t) {
    int idx = blockIdx.x * 256 + threadIdx.x;
    if (idx < COUT) {
        float s = g[idx] * rsqrtf(v[idx] + EPS_BN);
        t[idx] = bb[idx] - m[idx] * s;
    }
    if (idx < 9 * CIN * COUT) {
        constexpr int CCS = CIN / 32;
        int kk = idx & 31;
        int rest = idx >> 5;
        int n = rest & (COUT - 1);
        int chunk = rest / COUT;
        int tap = chunk / CCS;
        int cc  = chunk & (CCS - 1);
        int ci = cc * 32 + kk;
        float s = g[n] * rsqrtf(v[n] + EPS_BN);
        wp[idx] = f2bf(w[(n * CIN + ci) * 9 + tap] * s);
    }
}

// ---- conv1 (2->64, 3x3, stride (2,1), pad 1) + BN + ReLU, NHWC bf16 out ----
__global__ void conv1_kernel(const float* __restrict__ x, const float* __restrict__ sig,
                             const float* __restrict__ w1f, const float* __restrict__ t1,
                             unsigned short* __restrict__ h1) {
    __shared__ float xs[F0 * K], ssg[F0 * K], wsh[C1 * 19], bsh[C1];
    int b = blockIdx.x, t = threadIdx.x;
    for (int i = t; i < F0 * K; i += 256) {
        xs[i]  = x[(size_t)b * F0 * K + i];
        ssg[i] = sig[(size_t)b * F0 * K + i] * 10.0f;
    }
    for (int i = t; i < C1 * 18; i += 256) {
        int c = i / 18, r = i % 18;
        wsh[c * 19 + r] = w1f[i];
    }
    if (t < C1) bsh[t] = t1[t];
    __syncthreads();
    int c = t & 63, pg = t >> 6;
    for (int p = pg; p < F1 * K; p += 4) {
        int f = p / K, k = p % K;
        float acc = bsh[c];
        #pragma unroll
        for (int df = 0; df < 3; ++df) {
            int fi = 2 * f + df - 1;
            if (fi < 0 || fi >= F0) continue;
            #pragma unroll
            for (int dk = 0; dk < 3; ++dk) {
                int ki = k + dk - 1;
                if (ki < 0 || ki >= K) continue;
                acc = fmaf(xs[fi * K + ki],  wsh[c * 19 + df * 3 + dk], acc);
                acc = fmaf(ssg[fi * K + ki], wsh[c * 19 + 9 + df * 3 + dk], acc);
            }
        }
        h1[(((size_t)b * F1 + f) * K + k) * C1 + c] = f2bf(fmaxf(acc, 0.f));
    }
}

// ---- conv2 as MFMA GEMM: round-11 G=4 structure (proven in the 460us
// config), staging switched to by-fi planes (NP=9 vs 12 tiles: 25% less
// staging traffic, LDS 24.6->18.4KB). Same registers, same MINW=4.
template<int CIN, int COUT, int FIN, int MINW>
__launch_bounds__(256, MINW)
__global__ void conv_mfma(const unsigned short* __restrict__ hin,
                          const unsigned short* __restrict__ wp,
                          const float* __restrict__ tb,
                          const unsigned short* __restrict__ zero16,
                          unsigned short* __restrict__ hout) {
    constexpr int G = 4;
    constexpr int CHW = CIN / 8;
    constexpr int LOGC = (CHW == 16) ? 4 : 3;
    constexpr int NP = 2 * G + 1;            // fi planes: pf = 2g+df in [0,8]
    constexpr int NT = COUT / 64;
    constexpr int CCS = CIN / 32;
    constexpr int NIT = 9 * CCS;
    __shared__ alignas(16) unsigned short lin[NP * 16 * CIN];

    const int b = blockIdx.y;
    const int f2base = blockIdx.x * G;
    const int t = threadIdx.x;

    // by-fi staging: plane pf (fi = 2*f2base+pf-1), row p (kin=p-1), chunk
    // c8 pre-swizzled (c8^(p&7)). Pad rows pull from zeroed global block;
    // tail is wave-granular so gl_lds16 always sees full waves.
    constexpr int TOT = NP * 16 * CHW;
    for (int i = t; i < TOT; i += 256) {
        int c8 = i & (CHW - 1);
        int row = i >> LOGC;
        int p = row & 15;
        int pf = row >> 4;
        int kin = p - 1;
        int fi = 2 * f2base + pf - 1;
        bool valid = (kin >= 0) & (kin < K) & (fi >= 0);
        const unsigned short* src = valid
            ? hin + (((size_t)(b * FIN + fi)) * K + kin) * CIN + ((c8 ^ (p & 7)) << 3)
            : zero16;
        gl_lds16(src, &lin[i * 8]);
    }
    __syncthreads();

    const int lane = t & 63;
    const int wave = t >> 6;
    const int m = lane & 15;
    const int quad = lane >> 4;
    const int nBase = wave * (COUT / 4);

    f32x4 acc[G][NT];
    #pragma unroll
    for (int nt = 0; nt < NT; ++nt) {
        float bias = tb[nBase + nt * 16 + m];
        #pragma unroll
        for (int g = 0; g < G; ++g)
            acc[g][nt] = f32x4{bias, bias, bias, bias};
    }

    auto loadA = [&](int it, bf16x8* av) {
        int df = it / (3 * CCS), dk = (it / CCS) % 3, cc = it % CCS;
        int p = m + dk; p = (p > 15) ? 15 : p;
        int cidx = (((cc * 4 + quad) ^ (p & 7)) << 3);
        #pragma unroll
        for (int g = 0; g < G; ++g)
            av[g] = *(const bf16x8*)&lin[((2 * g + df) * 16 + p) * CIN + cidx];
    };
    auto loadB = [&](int it, bf16x8* bv) {
        int df = it / (3 * CCS), dk = (it / CCS) % 3, cc = it % CCS;
        int chunk = (df * 3 + dk) * CCS + cc;
        #pragma unroll
        for (int nt = 0; nt < NT; ++nt)
            bv[nt] = *(const bf16x8*)(wp + (((chunk * COUT + nBase + nt * 16 + m)) << 5) + quad * 8);
    };
    auto domfma = [&](bf16x8* av, bf16x8* bv) {
        #pragma unroll
        for (int g = 0; g < G; ++g)
            #pragma unroll
            for (int nt = 0; nt < NT; ++nt)
                acc[g][nt] = __builtin_amdgcn_mfma_f32_16x16x32_bf16(av[g], bv[nt], acc[g][nt], 0, 0, 0);
    };

    bf16x8 av[G], bA[NT], bB[NT];
    loadB(0, bA);
    #pragma unroll
    for (int it = 0; it < NIT; it += 2) {
        loadB(it + 1, bB);
        loadA(it, av);
        domfma(av, bA);
        if (it + 2 < NIT) loadB(it + 2, bA);
        loadA(it + 1, av);
        domfma(av, bB);
    }

    #pragma unroll
    for (int g = 0; g < G; ++g) {
        size_t rowbase = ((size_t)(b * (FIN / 2) + f2base + g)) * K;
        #pragma unroll
        for (int nt = 0; nt < NT; ++nt) {
            int col = nBase + nt * 16 + m;
            #pragma unroll
            for (int i = 0; i < 4; ++i) {
                int row = quad * 4 + i;
                if (row < K)
                    hout[(rowbase + row) * COUT + col] = f2bf(fmaxf(acc[g][nt][i], 0.f));
            }
        }
    }
}

// ---- conv3 + fused conv4: round-11 body (169us, 84 VGPR, no spill),
// staging switched to by-fi planes (LDS 49.6->37.4KB, 25% less staging).
template<int CIN, int COUT, int FIN, int MINW>
__launch_bounds__(256, MINW)
__global__ void conv_mfma_fused(const unsigned short* __restrict__ hin,
                                const unsigned short* __restrict__ wp,
                                const float* __restrict__ tb,
                                const unsigned short* __restrict__ zero16,
                                const float* __restrict__ w4,
                                float* __restrict__ pb) {
    constexpr int G = 4;
    constexpr int CHW = CIN / 8;
    constexpr int LOGC = (CHW == 16) ? 4 : 3;
    constexpr int NP = 2 * G + 1;            // fi planes: pf = 2g+df in [0,8]
    constexpr int NT = COUT / 64;
    constexpr int CCS = CIN / 32;
    constexpr int NIT = 9 * CCS;
    __shared__ alignas(16) unsigned short lin[NP * 16 * CIN];
    __shared__ float red[4][4][4][2];        // [wave][quad][i][j]

    const int b = blockIdx.y;
    const int f2base = blockIdx.x * G;
    const int t = threadIdx.x;

    constexpr int TOT = NP * 16 * CHW;
    for (int i = t; i < TOT; i += 256) {
        int c8 = i & (CHW - 1);
        int row = i >> LOGC;
        int p = row & 15;
        int pf = row >> 4;
        int kin = p - 1;
        int fi = 2 * f2base + pf - 1;
        bool valid = (kin >= 0) & (kin < K) & (fi >= 0);
        const unsigned short* src = valid
            ? hin + (((size_t)(b * FIN + fi)) * K + kin) * CIN + ((c8 ^ (p & 7)) << 3)
            : zero16;
        gl_lds16(src, &lin[i * 8]);
    }
    __syncthreads();

    const int lane = t & 63;
    const int wave = t >> 6;
    const int m = lane & 15;
    const int quad = lane >> 4;
    const int nBase = wave * (COUT / 4);

    f32x4 acc[G][NT];
    #pragma unroll
    for (int nt = 0; nt < NT; ++nt) {
        float bias = tb[nBase + nt * 16 + m];
        #pragma unroll
        for (int g = 0; g < G; ++g)
            acc[g][nt] = f32x4{bias, bias, bias, bias};
    }

    auto loadA = [&](int it, bf16x8* av) {
        int df = it / (3 * CCS), dk = (it / CCS) % 3, cc = it % CCS;
        int p = m + dk; p = (p > 15) ? 15 : p;
        int cidx = (((cc * 4 + quad) ^ (p & 7)) << 3);
        #pragma unroll
        for (int g = 0; g < G; ++g)
            av[g] = *(const bf16x8*)&lin[((2 * g + df) * 16 + p) * CIN + cidx];
    };
    auto loadB = [&](int it, bf16x8* bv) {
        int df = it / (3 * CCS), dk = (it / CCS) % 3, cc = it % CCS;
        int chunk = (df * 3 + dk) * CCS + cc;
        #pragma unroll
        for (int nt = 0; nt < NT; ++nt)
            bv[nt] = *(const bf16x8*)(wp + (((chunk * COUT + nBase + nt * 16 + m)) << 5) + quad * 8);
    };
    auto domfma = [&](bf16x8* av, bf16x8* bv) {
        #pragma unroll
        for (int g = 0; g < G; ++g)
            #pragma unroll
            for (int nt = 0; nt < NT; ++nt)
                acc[g][nt] = __builtin_amdgcn_mfma_f32_16x16x32_bf16(av[g], bv[nt], acc[g][nt], 0, 0, 0);
    };

    bf16x8 av[G], bA[NT], bB[NT];
    loadB(0, bA);
    #pragma unroll
    for (int it = 0; it < NIT; it += 2) {
        loadB(it + 1, bB);
        loadA(it, av);
        domfma(av, bA);
        if (it + 2 < NIT) loadB(it + 2, bA);
        loadA(it + 1, av);
        domfma(av, bB);
    }

    // ---- fused conv4 epilogue ----
    float part[4][2];
    #pragma unroll
    for (int i = 0; i < 4; ++i) { part[i][0] = 0.f; part[i][1] = 0.f; }
    #pragma unroll
    for (int g = 0; g < G; ++g) {
        int f = f2base + g;
        #pragma unroll
        for (int nt = 0; nt < NT; ++nt) {
            int c = nBase + nt * 16 + m;
            float w0 = w4[(0 * COUT + c) * F3 + f];
            float w1 = w4[(1 * COUT + c) * F3 + f];
            #pragma unroll
            for (int i = 0; i < 4; ++i) {
                float v = fmaxf(acc[g][nt][i], 0.f);
                part[i][0] = fmaf(v, w0, part[i][0]);
                part[i][1] = fmaf(v, w1, part[i][1]);
            }
        }
    }
    if (quad == 3) { part[2][0] = 0.f; part[2][1] = 0.f; part[3][0] = 0.f; part[3][1] = 0.f; }
    #pragma unroll
    for (int i = 0; i < 4; ++i)
        #pragma unroll
        for (int j = 0; j < 2; ++j) {
            float v = part[i][j];
            v += __shfl_xor(v, 1, 64);
            v += __shfl_xor(v, 2, 64);
            v += __shfl_xor(v, 4, 64);
            v += __shfl_xor(v, 8, 64);
            part[i][j] = v;
        }
    if (m == 0) {
        #pragma unroll
        for (int i = 0; i < 4; ++i) {
            red[wave][quad][i][0] = part[i][0];
            red[wave][quad][i][1] = part[i][1];
        }
    }
    __syncthreads();
    if (t < 2 * K) {
        int k = t >> 1, j = t & 1;
        float s = red[0][k >> 2][k & 3][j] + red[1][k >> 2][k & 3][j]
                + red[2][k >> 2][k & 3][j] + red[3][k >> 2][k & 3][j];
        pb[((size_t)b * 2 + blockIdx.x) * (2 * K) + t] = s;
    }
}

// ---- final: out[b,k,j] = pb[b][0][...] + pb[b][1][...] ----
__global__ void fin_kernel(const float* __restrict__ pb, float* __restrict__ out) {
    int idx = blockIdx.x * 256 + threadIdx.x;
    if (idx < B * 2 * K) {
        int b = idx / (2 * K), r = idx % (2 * K);
        out[idx] = pb[(size_t)b * (4 * K) + r] + pb[(size_t)b * (4 * K) + 2 * K + r];
    }
}

extern "C" void kernel_launch(void* const* d_in, const int* in_sizes, int n_in,
                              void* d_out, int out_size, void* d_ws, size_t ws_size,
                              hipStream_t stream) {
    const float* x   = (const float*)d_in[0];
    const float* sig = (const float*)d_in[1];
    const float* w1  = (const float*)d_in[2];
    const float* w2  = (const float*)d_in[3];
    const float* w3  = (const float*)d_in[4];
    const float* w4  = (const float*)d_in[5];
    const float* g1  = (const float*)d_in[6];
    const float* b1  = (const float*)d_in[7];
    const float* m1  = (const float*)d_in[8];
    const float* v1  = (const float*)d_in[9];
    const float* g2  = (const float*)d_in[10];
    const float* b2  = (const float*)d_in[11];
    const float* m2  = (const float*)d_in[12];
    const float* v2  = (const float*)d_in[13];
    const float* g3  = (const float*)d_in[14];
    const float* b3  = (const float*)d_in[15];
    const float* m3  = (const float*)d_in[16];
    const float* v3  = (const float*)d_in[17];

    char* ws = (char*)d_ws;
    size_t off = 0;
    auto alloc = [&](size_t bytes) {
        char* p = ws + off;
        off += (bytes + 255) & ~(size_t)255;
        return p;
    };
    unsigned short* h1  = (unsigned short*)alloc((size_t)B * F1 * K * C1 * 2);
    unsigned short* h2  = (unsigned short*)alloc((size_t)B * F2 * K * C2 * 2);
    float* w1f = (float*)alloc((size_t)C1 * 2 * 9 * 4);
    float* t1  = (float*)alloc((size_t)C1 * 4);
    unsigned short* wp2 = (unsigned short*)alloc((size_t)9 * C1 * C2 * 2);
    float* t2  = (float*)alloc((size_t)C2 * 4);
    unsigned short* wp3 = (unsigned short*)alloc((size_t)9 * C2 * C3 * 2);
    float* t3  = (float*)alloc((size_t)C3 * 4);
    float* zbuf = (float*)alloc(16);
    float* pb   = (float*)alloc((size_t)B * 2 * 2 * K * 4);   // per-block conv4 partials

    repack_w1<<<(C1 * 2 * 9 + 255) / 256, 256, 0, stream>>>(w1, g1, b1, m1, v1, w1f, t1, zbuf);
    repack_mfma<C1, C2><<<(9 * C1 * C2 + 255) / 256, 256, 0, stream>>>(w2, g2, b2, m2, v2, wp2, t2);
    repack_mfma<C2, C3><<<(9 * C2 * C3 + 255) / 256, 256, 0, stream>>>(w3, g3, b3, m3, v3, wp3, t3);

    conv1_kernel<<<B, 256, 0, stream>>>(x, sig, w1f, t1, h1);
    // conv2: G=4 by-fi -> grid (4, B); LDS 18.4KB; MINW=4 (demand ~108 <= 128)
    conv_mfma<C1, C2, F1, 4><<<dim3(F1 / 2 / 4, B), 256, 0, stream>>>(h1, wp2, t2, (const unsigned short*)zbuf, h2);
    // conv3 + fused conv4: G=4 by-fi -> grid (2, B); LDS 37.4KB; MINW=3
    conv_mfma_fused<C2, C3, F2, 3><<<dim3(F2 / 2 / 4, B), 256, 0, stream>>>(h2, wp3, t3, (const unsigned short*)zbuf, w4, pb);
    fin_kernel<<<(B * 2 * K + 255) / 256, 256, 0, stream>>>(pb, (float*)d_out);
}

// Round 14
// 460.148 us; speedup vs baseline: 1.3794x; 1.3794x over previous
//
#include <hip/hip_runtime.h>
#include <hip/hip_bf16.h>

#define EPS_BN 1e-5f

constexpr int B  = 2048, F0 = 64, K = 14;
constexpr int C1 = 64,  F1 = 32;
constexpr int C2 = 128, F2 = 16;
constexpr int C3 = 256, F3 = 8;

typedef __attribute__((ext_vector_type(8))) short bf16x8;
typedef __attribute__((ext_vector_type(4))) float f32x4;

__device__ __forceinline__ float bf2f(unsigned short u) {
    union { unsigned int i; float f; } x; x.i = ((unsigned int)u) << 16; return x.f;
}
__device__ __forceinline__ unsigned short f2bf(float f) {
    union { float f; unsigned int i; } x; x.f = f;
    unsigned int r = (x.i + 0x7fffu + ((x.i >> 16) & 1u)) >> 16;
    return (unsigned short)r;
}

// async global->LDS 16B copy. HW: LDS dest = wave-uniform base + lane*16.
// Callers must keep whole waves active with per-lane-consecutive dests.
__device__ __forceinline__ void gl_lds16(const void* g, void* l) {
    __builtin_amdgcn_global_load_lds(
        (const __attribute__((address_space(1))) unsigned int*)g,
        (__attribute__((address_space(3))) unsigned int*)l,
        16, 0, 0);
}

// ---- fold BN into conv1 weights; also zero the 16B pad-source block ----
__global__ void repack_w1(const float* __restrict__ w1, const float* __restrict__ g,
                          const float* __restrict__ bb, const float* __restrict__ m,
                          const float* __restrict__ v, float* __restrict__ w1f,
                          float* __restrict__ t1, float* __restrict__ zbuf) {
    int i = blockIdx.x * 256 + threadIdx.x;
    if (i < 4) zbuf[i] = 0.0f;
    if (i < C1) {
        float s = g[i] * rsqrtf(v[i] + EPS_BN);
        t1[i] = bb[i] - m[i] * s;
    }
    if (i < C1 * 2 * 9) {
        int c = i / 18;
        float s = g[c] * rsqrtf(v[c] + EPS_BN);
        w1f[i] = w1[i] * s;
    }
}

// ---- repack conv weights into MFMA B-fragment layout, bf16, BN-folded ----
// wp[((chunk*COUT + n)*32) + kk] = W[tap][ci][n]*s[n], chunk=tap*(CIN/32)+cc, ci=cc*32+kk
template<int CIN, int COUT>
__global__ void repack_mfma(const float* __restrict__ w, const float* __restrict__ g,
                            const float* __restrict__ bb, const float* __restrict__ m,
                            const float* __restrict__ v, unsigned short* __restrict__ wp,
                            float* __restrict__ t) {
    int idx = blockIdx.x * 256 + threadIdx.x;
    if (idx < COUT) {
        float s = g[idx] * rsqrtf(v[idx] + EPS_BN);
        t[idx] = bb[idx] - m[idx] * s;
    }
    if (idx < 9 * CIN * COUT) {
        constexpr int CCS = CIN / 32;
        int kk = idx & 31;
        int rest = idx >> 5;
        int n = rest & (COUT - 1);
        int chunk = rest / COUT;
        int tap = chunk / CCS;
        int cc  = chunk & (CCS - 1);
        int ci = cc * 32 + kk;
        float s = g[n] * rsqrtf(v[n] + EPS_BN);
        wp[idx] = f2bf(w[(n * CIN + ci) * 9 + tap] * s);
    }
}

// ---- conv1 (2->64, 3x3, stride (2,1), pad 1) + BN + ReLU, NHWC bf16 out ----
__global__ void conv1_kernel(const float* __restrict__ x, const float* __restrict__ sig,
                             const float* __restrict__ w1f, const float* __restrict__ t1,
                             unsigned short* __restrict__ h1) {
    __shared__ float xs[F0 * K], ssg[F0 * K], wsh[C1 * 19], bsh[C1];
    int b = blockIdx.x, t = threadIdx.x;
    for (int i = t; i < F0 * K; i += 256) {
        xs[i]  = x[(size_t)b * F0 * K + i];
        ssg[i] = sig[(size_t)b * F0 * K + i] * 10.0f;
    }
    for (int i = t; i < C1 * 18; i += 256) {
        int c = i / 18, r = i % 18;
        wsh[c * 19 + r] = w1f[i];
    }
    if (t < C1) bsh[t] = t1[t];
    __syncthreads();
    int c = t & 63, pg = t >> 6;
    for (int p = pg; p < F1 * K; p += 4) {
        int f = p / K, k = p % K;
        float acc = bsh[c];
        #pragma unroll
        for (int df = 0; df < 3; ++df) {
            int fi = 2 * f + df - 1;
            if (fi < 0 || fi >= F0) continue;
            #pragma unroll
            for (int dk = 0; dk < 3; ++dk) {
                int ki = k + dk - 1;
                if (ki < 0 || ki >= K) continue;
                acc = fmaf(xs[fi * K + ki],  wsh[c * 19 + df * 3 + dk], acc);
                acc = fmaf(ssg[fi * K + ki], wsh[c * 19 + 9 + df * 3 + dk], acc);
            }
        }
        h1[(((size_t)b * F1 + f) * K + k) * C1 + c] = f2bf(fmaxf(acc, 0.f));
    }
}

// ---- conv2 as MFMA GEMM: round-2 structure VERBATIM (proven 76 VGPR, no
// spill, 522us pipeline). G=4 per-(g,df) tiles, flat it-loop, 2-deep bv rot.
template<int CIN, int COUT, int FIN, int MINW>
__launch_bounds__(256, MINW)
__global__ void conv_mfma(const unsigned short* __restrict__ hin,
                          const unsigned short* __restrict__ wp,
                          const float* __restrict__ tb,
                          const unsigned short* __restrict__ zero16,
                          unsigned short* __restrict__ hout) {
    constexpr int G = 4;
    constexpr int CHW = CIN / 8;
    constexpr int LOGC = (CHW == 16) ? 4 : 3;
    constexpr int NT = COUT / 64;
    constexpr int CCS = CIN / 32;
    constexpr int NIT = 9 * CCS;
    __shared__ alignas(16) unsigned short lin[G * 3 * 16 * CIN];

    const int b = blockIdx.y;
    const int f2base = blockIdx.x * G;
    const int t = threadIdx.x;

    {
        constexpr int TOT = G * 3 * 16 * CHW;
        #pragma unroll
        for (int i = t; i < TOT; i += 256) {
            int c8 = i & (CHW - 1);
            int row = i >> LOGC;
            int p = row & 15;
            int tile = row >> 4;
            int df = tile % 3, g = tile / 3;
            int kin = p - 1;
            int fi = 2 * (f2base + g) + df - 1;
            bool valid = (kin >= 0) & (kin < K) & (fi >= 0);
            const unsigned short* src = valid
                ? hin + (((size_t)(b * FIN + fi)) * K + kin) * CIN + ((c8 ^ (p & 7)) << 3)
                : zero16;
            gl_lds16(src, &lin[i * 8]);
        }
    }
    __syncthreads();

    const int lane = t & 63;
    const int wave = t >> 6;
    const int m = lane & 15;
    const int quad = lane >> 4;
    const int nBase = wave * (COUT / 4);

    f32x4 acc[G][NT];
    #pragma unroll
    for (int nt = 0; nt < NT; ++nt) {
        float bias = tb[nBase + nt * 16 + m];
        #pragma unroll
        for (int g = 0; g < G; ++g)
            acc[g][nt] = f32x4{bias, bias, bias, bias};
    }

    auto loadA = [&](int it, bf16x8* av) {
        int df = it / (3 * CCS), dk = (it / CCS) % 3, cc = it % CCS;
        int p = m + dk; p = (p > 15) ? 15 : p;
        int cidx = (((cc * 4 + quad) ^ (p & 7)) << 3);
        #pragma unroll
        for (int g = 0; g < G; ++g)
            av[g] = *(const bf16x8*)&lin[((g * 3 + df) * 16 + p) * CIN + cidx];
    };
    auto loadB = [&](int it, bf16x8* bv) {
        int df = it / (3 * CCS), dk = (it / CCS) % 3, cc = it % CCS;
        int chunk = (df * 3 + dk) * CCS + cc;
        #pragma unroll
        for (int nt = 0; nt < NT; ++nt)
            bv[nt] = *(const bf16x8*)(wp + (((chunk * COUT + nBase + nt * 16 + m)) << 5) + quad * 8);
    };
    auto domfma = [&](bf16x8* av, bf16x8* bv) {
        #pragma unroll
        for (int g = 0; g < G; ++g)
            #pragma unroll
            for (int nt = 0; nt < NT; ++nt)
                acc[g][nt] = __builtin_amdgcn_mfma_f32_16x16x32_bf16(av[g], bv[nt], acc[g][nt], 0, 0, 0);
    };

    bf16x8 av[G], bA[NT], bB[NT];
    loadB(0, bA);
    #pragma unroll
    for (int it = 0; it < NIT; it += 2) {
        loadB(it + 1, bB);
        loadA(it, av);
        domfma(av, bA);
        if (it + 2 < NIT) loadB(it + 2, bA);
        loadA(it + 1, av);
        domfma(av, bB);
    }

    #pragma unroll
    for (int g = 0; g < G; ++g) {
        size_t rowbase = ((size_t)(b * (FIN / 2) + f2base + g)) * K;
        #pragma unroll
        for (int nt = 0; nt < NT; ++nt) {
            int col = nBase + nt * 16 + m;
            #pragma unroll
            for (int i = 0; i < 4; ++i) {
                int row = quad * 4 + i;
                if (row < K)
                    hout[(rowbase + row) * COUT + col] = f2bf(fmaxf(acc[g][nt][i], 0.f));
            }
        }
    }
}

// ---- conv3 + fused conv4 (round-11, VERBATIM — 169us, 84 VGPR, no spill) ----
template<int CIN, int COUT, int FIN, int MINW>
__launch_bounds__(256, MINW)
__global__ void conv_mfma_fused(const unsigned short* __restrict__ hin,
                                const unsigned short* __restrict__ wp,
                                const float* __restrict__ tb,
                                const unsigned short* __restrict__ zero16,
                                const float* __restrict__ w4,
                                float* __restrict__ pb) {
    constexpr int G = 4;
    constexpr int CHW = CIN / 8;
    constexpr int LOGC = (CHW == 16) ? 4 : 3;
    constexpr int NT = COUT / 64;
    constexpr int CCS = CIN / 32;
    constexpr int NIT = 9 * CCS;
    __shared__ alignas(16) unsigned short lin[G * 3 * 16 * CIN];
    __shared__ float red[4][4][4][2];        // [wave][quad][i][j]

    const int b = blockIdx.y;
    const int f2base = blockIdx.x * G;
    const int t = threadIdx.x;

    {
        constexpr int TOT = G * 3 * 16 * CHW;
        #pragma unroll
        for (int i = t; i < TOT; i += 256) {
            int c8 = i & (CHW - 1);
            int row = i >> LOGC;
            int p = row & 15;
            int tile = row >> 4;
            int df = tile % 3, g = tile / 3;
            int kin = p - 1;
            int fi = 2 * (f2base + g) + df - 1;
            bool valid = (kin >= 0) & (kin < K) & (fi >= 0);
            const unsigned short* src = valid
                ? hin + (((size_t)(b * FIN + fi)) * K + kin) * CIN + ((c8 ^ (p & 7)) << 3)
                : zero16;
            gl_lds16(src, &lin[i * 8]);
        }
    }
    __syncthreads();

    const int lane = t & 63;
    const int wave = t >> 6;
    const int m = lane & 15;
    const int quad = lane >> 4;
    const int nBase = wave * (COUT / 4);

    f32x4 acc[G][NT];
    #pragma unroll
    for (int nt = 0; nt < NT; ++nt) {
        float bias = tb[nBase + nt * 16 + m];
        #pragma unroll
        for (int g = 0; g < G; ++g)
            acc[g][nt] = f32x4{bias, bias, bias, bias};
    }

    auto loadA = [&](int it, bf16x8* av) {
        int df = it / (3 * CCS), dk = (it / CCS) % 3, cc = it % CCS;
        int p = m + dk; p = (p > 15) ? 15 : p;
        int cidx = (((cc * 4 + quad) ^ (p & 7)) << 3);
        #pragma unroll
        for (int g = 0; g < G; ++g)
            av[g] = *(const bf16x8*)&lin[((g * 3 + df) * 16 + p) * CIN + cidx];
    };
    auto loadB = [&](int it, bf16x8* bv) {
        int df = it / (3 * CCS), dk = (it / CCS) % 3, cc = it % CCS;
        int chunk = (df * 3 + dk) * CCS + cc;
        #pragma unroll
        for (int nt = 0; nt < NT; ++nt)
            bv[nt] = *(const bf16x8*)(wp + (((chunk * COUT + nBase + nt * 16 + m)) << 5) + quad * 8);
    };
    auto domfma = [&](bf16x8* av, bf16x8* bv) {
        #pragma unroll
        for (int g = 0; g < G; ++g)
            #pragma unroll
            for (int nt = 0; nt < NT; ++nt)
                acc[g][nt] = __builtin_amdgcn_mfma_f32_16x16x32_bf16(av[g], bv[nt], acc[g][nt], 0, 0, 0);
    };

    bf16x8 av[G], bA[NT], bB[NT];
    loadB(0, bA);
    #pragma unroll
    for (int it = 0; it < NIT; it += 2) {
        loadB(it + 1, bB);
        loadA(it, av);
        domfma(av, bA);
        if (it + 2 < NIT) loadB(it + 2, bA);
        loadA(it + 1, av);
        domfma(av, bB);
    }

    // ---- fused conv4 epilogue ----
    float part[4][2];
    #pragma unroll
    for (int i = 0; i < 4; ++i) { part[i][0] = 0.f; part[i][1] = 0.f; }
    #pragma unroll
    for (int g = 0; g < G; ++g) {
        int f = f2base + g;
        #pragma unroll
        for (int nt = 0; nt < NT; ++nt) {
            int c = nBase + nt * 16 + m;
            float w0 = w4[(0 * COUT + c) * F3 + f];
            float w1 = w4[(1 * COUT + c) * F3 + f];
            #pragma unroll
            for (int i = 0; i < 4; ++i) {
                float v = fmaxf(acc[g][nt][i], 0.f);
                part[i][0] = fmaf(v, w0, part[i][0]);
                part[i][1] = fmaf(v, w1, part[i][1]);
            }
        }
    }
    if (quad == 3) { part[2][0] = 0.f; part[2][1] = 0.f; part[3][0] = 0.f; part[3][1] = 0.f; }
    #pragma unroll
    for (int i = 0; i < 4; ++i)
        #pragma unroll
        for (int j = 0; j < 2; ++j) {
            float v = part[i][j];
            v += __shfl_xor(v, 1, 64);
            v += __shfl_xor(v, 2, 64);
            v += __shfl_xor(v, 4, 64);
            v += __shfl_xor(v, 8, 64);
            part[i][j] = v;
        }
    if (m == 0) {
        #pragma unroll
        for (int i = 0; i < 4; ++i) {
            red[wave][quad][i][0] = part[i][0];
            red[wave][quad][i][1] = part[i][1];
        }
    }
    __syncthreads();
    if (t < 2 * K) {
        int k = t >> 1, j = t & 1;
        float s = red[0][k >> 2][k & 3][j] + red[1][k >> 2][k & 3][j]
                + red[2][k >> 2][k & 3][j] + red[3][k >> 2][k & 3][j];
        pb[((size_t)b * 2 + blockIdx.x) * (2 * K) + t] = s;
    }
}

// ---- final: out[b,k,j] = pb[b][0][...] + pb[b][1][...] ----
__global__ void fin_kernel(const float* __restrict__ pb, float* __restrict__ out) {
    int idx = blockIdx.x * 256 + threadIdx.x;
    if (idx < B * 2 * K) {
        int b = idx / (2 * K), r = idx % (2 * K);
        out[idx] = pb[(size_t)b * (4 * K) + r] + pb[(size_t)b * (4 * K) + 2 * K + r];
    }
}

extern "C" void kernel_launch(void* const* d_in, const int* in_sizes, int n_in,
                              void* d_out, int out_size, void* d_ws, size_t ws_size,
                              hipStream_t stream) {
    const float* x   = (const float*)d_in[0];
    const float* sig = (const float*)d_in[1];
    const float* w1  = (const float*)d_in[2];
    const float* w2  = (const float*)d_in[3];
    const float* w3  = (const float*)d_in[4];
    const float* w4  = (const float*)d_in[5];
    const float* g1  = (const float*)d_in[6];
    const float* b1  = (const float*)d_in[7];
    const float* m1  = (const float*)d_in[8];
    const float* v1  = (const float*)d_in[9];
    const float* g2  = (const float*)d_in[10];
    const float* b2  = (const float*)d_in[11];
    const float* m2  = (const float*)d_in[12];
    const float* v2  = (const float*)d_in[13];
    const float* g3  = (const float*)d_in[14];
    const float* b3  = (const float*)d_in[15];
    const float* m3  = (const float*)d_in[16];
    const float* v3  = (const float*)d_in[17];

    char* ws = (char*)d_ws;
    size_t off = 0;
    auto alloc = [&](size_t bytes) {
        char* p = ws + off;
        off += (bytes + 255) & ~(size_t)255;
        return p;
    };
    unsigned short* h1  = (unsigned short*)alloc((size_t)B * F1 * K * C1 * 2);
    unsigned short* h2  = (unsigned short*)alloc((size_t)B * F2 * K * C2 * 2);
    float* w1f = (float*)alloc((size_t)C1 * 2 * 9 * 4);
    float* t1  = (float*)alloc((size_t)C1 * 4);
    unsigned short* wp2 = (unsigned short*)alloc((size_t)9 * C1 * C2 * 2);
    float* t2  = (float*)alloc((size_t)C2 * 4);
    unsigned short* wp3 = (unsigned short*)alloc((size_t)9 * C2 * C3 * 2);
    float* t3  = (float*)alloc((size_t)C3 * 4);
    float* zbuf = (float*)alloc(16);
    float* pb   = (float*)alloc((size_t)B * 2 * 2 * K * 4);   // per-block conv4 partials

    repack_w1<<<(C1 * 2 * 9 + 255) / 256, 256, 0, stream>>>(w1, g1, b1, m1, v1, w1f, t1, zbuf);
    repack_mfma<C1, C2><<<(9 * C1 * C2 + 255) / 256, 256, 0, stream>>>(w2, g2, b2, m2, v2, wp2, t2);
    repack_mfma<C2, C3><<<(9 * C2 * C3 + 255) / 256, 256, 0, stream>>>(w3, g3, b3, m3, v3, wp3, t3);

    conv1_kernel<<<B, 256, 0, stream>>>(x, sig, w1f, t1, h1);
    // conv2: round-2 structure, G=4 -> grid (4, B)
    conv_mfma<C1, C2, F1, 4><<<dim3(F1 / 2 / 4, B), 256, 0, stream>>>(h1, wp2, t2, (const unsigned short*)zbuf, h2);
    // conv3 + fused conv4: grid (2, B); writes 28-float partials per block
    conv_mfma_fused<C2, C3, F2, 3><<<dim3(F2 / 2 / 4, B), 256, 0, stream>>>(h2, wp3, t3, (const unsigned short*)zbuf, w4, pb);
    fin_kernel<<<(B * 2 * K + 255) / 256, 256, 0, stream>>>(pb, (float*)d_out);
}

// Round 15
// 395.661 us; speedup vs baseline: 1.6042x; 1.1630x over previous
//
#include <hip/hip_runtime.h>
#include <hip/hip_bf16.h>

#define EPS_BN 1e-5f

constexpr int B  = 2048, F0 = 64, K = 14;
constexpr int C1 = 64,  F1 = 32;
constexpr int C2 = 128, F2 = 16;
constexpr int C3 = 256, F3 = 8;

typedef __attribute__((ext_vector_type(8))) short bf16x8;
typedef __attribute__((ext_vector_type(4))) float f32x4;

__device__ __forceinline__ float bf2f(unsigned short u) {
    union { unsigned int i; float f; } x; x.i = ((unsigned int)u) << 16; return x.f;
}
__device__ __forceinline__ unsigned short f2bf(float f) {
    union { float f; unsigned int i; } x; x.f = f;
    unsigned int r = (x.i + 0x7fffu + ((x.i >> 16) & 1u)) >> 16;
    return (unsigned short)r;
}

// async global->LDS 16B copy. HW: LDS dest = wave-uniform base + lane*16.
// Callers must keep whole waves active with per-lane-consecutive dests.
__device__ __forceinline__ void gl_lds16(const void* g, void* l) {
    __builtin_amdgcn_global_load_lds(
        (const __attribute__((address_space(1))) unsigned int*)g,
        (__attribute__((address_space(3))) unsigned int*)l,
        16, 0, 0);
}

// ---- fold BN into conv1 weights; also zero the 16B pad-source block ----
__global__ void repack_w1(const float* __restrict__ w1, const float* __restrict__ g,
                          const float* __restrict__ bb, const float* __restrict__ m,
                          const float* __restrict__ v, float* __restrict__ w1f,
                          float* __restrict__ t1, float* __restrict__ zbuf) {
    int i = blockIdx.x * 256 + threadIdx.x;
    if (i < 4) zbuf[i] = 0.0f;
    if (i < C1) {
        float s = g[i] * rsqrtf(v[i] + EPS_BN);
        t1[i] = bb[i] - m[i] * s;
    }
    if (i < C1 * 2 * 9) {
        int c = i / 18;
        float s = g[c] * rsqrtf(v[c] + EPS_BN);
        w1f[i] = w1[i] * s;
    }
}

// ---- repack conv weights into MFMA B-fragment layout, bf16, BN-folded ----
// wp[((chunk*COUT + n)*32) + kk] = W[tap][ci][n]*s[n], chunk=tap*(CIN/32)+cc, ci=cc*32+kk
template<int CIN, int COUT>
__global__ void repack_mfma(const float* __restrict__ w, const float* __restrict__ g,
                            const float* __restrict__ bb, const float* __restrict__ m,
                            const float* __restrict__ v, unsigned short* __restrict__ wp,
                            float* __restrict__ t) {
    int idx = blockIdx.x * 256 + threadIdx.x;
    if (idx < COUT) {
        float s = g[idx] * rsqrtf(v[idx] + EPS_BN);
        t[idx] = bb[idx] - m[idx] * s;
    }
    if (idx < 9 * CIN * COUT) {
        constexpr int CCS = CIN / 32;
        int kk = idx & 31;
        int rest = idx >> 5;
        int n = rest & (COUT - 1);
        int chunk = rest / COUT;
        int tap = chunk / CCS;
        int cc  = chunk & (CCS - 1);
        int ci = cc * 32 + kk;
        float s = g[n] * rsqrtf(v[n] + EPS_BN);
        wp[idx] = f2bf(w[(n * CIN + ci) * 9 + tap] * s);
    }
}

// ---- conv1 v2: 4 channels/thread, float4 weight reads, ushort4 stores ----
// Old version: 1 ch/thread -> scalar 2B stores (G13 pitfall) and 4x redundant
// xs/wsh LDS reads. New: wsh staged TRANSPOSED [tap][c] so 4 channels' weights
// are one float4 read; xs broadcast across the 16 lanes sharing a position;
// output ushort4 (8B/lane, 256B contiguous per 16-lane group). Same FMAs,
// ~4x fewer LDS ops and store instructions.
__global__ void conv1_kernel(const float* __restrict__ x, const float* __restrict__ sig,
                             const float* __restrict__ w1f, const float* __restrict__ t1,
                             unsigned short* __restrict__ h1) {
    __shared__ float xs[F0 * K], ssg[F0 * K], wsh2[18 * C1], bsh[C1];
    int b = blockIdx.x, t = threadIdx.x;
    // stage x/sig as float4 (F0*K = 896 = 224 float4)
    for (int i = t; i < F0 * K / 4; i += 256) {
        float4 xv = ((const float4*)(x + (size_t)b * F0 * K))[i];
        ((float4*)xs)[i] = xv;
        float4 sv = ((const float4*)(sig + (size_t)b * F0 * K))[i];
        sv.x *= 10.0f; sv.y *= 10.0f; sv.z *= 10.0f; sv.w *= 10.0f;
        ((float4*)ssg)[i] = sv;
    }
    // stage weights transposed: wsh2[r*C1 + c] = w1f[c*18 + r]
    for (int i = t; i < C1 * 18; i += 256) {
        int c = i / 18, r = i % 18;
        wsh2[r * C1 + c] = w1f[i];
    }
    if (t < C1) bsh[t] = t1[t];
    __syncthreads();
    const int c4 = (t & 15) * 4;
    const int pg = t >> 4;
    const float4 bias = *(const float4*)&bsh[c4];
    for (int pos = pg; pos < F1 * K; pos += 16) {
        int f = pos / K, k = pos % K;
        float a0 = bias.x, a1 = bias.y, a2 = bias.z, a3 = bias.w;
        #pragma unroll
        for (int df = 0; df < 3; ++df) {
            int fi = 2 * f + df - 1;
            if (fi < 0 || fi >= F0) continue;
            #pragma unroll
            for (int dk = 0; dk < 3; ++dk) {
                int ki = k + dk - 1;
                if (ki < 0 || ki >= K) continue;
                float xv = xs[fi * K + ki];
                float sv = ssg[fi * K + ki];
                float4 wx = *(const float4*)&wsh2[(df * 3 + dk) * C1 + c4];
                float4 ws = *(const float4*)&wsh2[(9 + df * 3 + dk) * C1 + c4];
                a0 = fmaf(xv, wx.x, fmaf(sv, ws.x, a0));
                a1 = fmaf(xv, wx.y, fmaf(sv, ws.y, a1));
                a2 = fmaf(xv, wx.z, fmaf(sv, ws.z, a2));
                a3 = fmaf(xv, wx.w, fmaf(sv, ws.w, a3));
            }
        }
        ushort4 o;
        o.x = f2bf(fmaxf(a0, 0.f));
        o.y = f2bf(fmaxf(a1, 0.f));
        o.z = f2bf(fmaxf(a2, 0.f));
        o.w = f2bf(fmaxf(a3, 0.f));
        *(ushort4*)&h1[(((size_t)b * F1 + f) * K + k) * C1 + c4] = o;
    }
}

// ---- conv2 as MFMA GEMM: round-2 structure VERBATIM (proven 76 VGPR, no
// spill, part of the 460us config). G=4 per-(g,df) tiles, 2-deep bv rot.
template<int CIN, int COUT, int FIN, int MINW>
__launch_bounds__(256, MINW)
__global__ void conv_mfma(const unsigned short* __restrict__ hin,
                          const unsigned short* __restrict__ wp,
                          const float* __restrict__ tb,
                          const unsigned short* __restrict__ zero16,
                          unsigned short* __restrict__ hout) {
    constexpr int G = 4;
    constexpr int CHW = CIN / 8;
    constexpr int LOGC = (CHW == 16) ? 4 : 3;
    constexpr int NT = COUT / 64;
    constexpr int CCS = CIN / 32;
    constexpr int NIT = 9 * CCS;
    __shared__ alignas(16) unsigned short lin[G * 3 * 16 * CIN];

    const int b = blockIdx.y;
    const int f2base = blockIdx.x * G;
    const int t = threadIdx.x;

    {
        constexpr int TOT = G * 3 * 16 * CHW;
        #pragma unroll
        for (int i = t; i < TOT; i += 256) {
            int c8 = i & (CHW - 1);
            int row = i >> LOGC;
            int p = row & 15;
            int tile = row >> 4;
            int df = tile % 3, g = tile / 3;
            int kin = p - 1;
            int fi = 2 * (f2base + g) + df - 1;
            bool valid = (kin >= 0) & (kin < K) & (fi >= 0);
            const unsigned short* src = valid
                ? hin + (((size_t)(b * FIN + fi)) * K + kin) * CIN + ((c8 ^ (p & 7)) << 3)
                : zero16;
            gl_lds16(src, &lin[i * 8]);
        }
    }
    __syncthreads();

    const int lane = t & 63;
    const int wave = t >> 6;
    const int m = lane & 15;
    const int quad = lane >> 4;
    const int nBase = wave * (COUT / 4);

    f32x4 acc[G][NT];
    #pragma unroll
    for (int nt = 0; nt < NT; ++nt) {
        float bias = tb[nBase + nt * 16 + m];
        #pragma unroll
        for (int g = 0; g < G; ++g)
            acc[g][nt] = f32x4{bias, bias, bias, bias};
    }

    auto loadA = [&](int it, bf16x8* av) {
        int df = it / (3 * CCS), dk = (it / CCS) % 3, cc = it % CCS;
        int p = m + dk; p = (p > 15) ? 15 : p;
        int cidx = (((cc * 4 + quad) ^ (p & 7)) << 3);
        #pragma unroll
        for (int g = 0; g < G; ++g)
            av[g] = *(const bf16x8*)&lin[((g * 3 + df) * 16 + p) * CIN + cidx];
    };
    auto loadB = [&](int it, bf16x8* bv) {
        int df = it / (3 * CCS), dk = (it / CCS) % 3, cc = it % CCS;
        int chunk = (df * 3 + dk) * CCS + cc;
        #pragma unroll
        for (int nt = 0; nt < NT; ++nt)
            bv[nt] = *(const bf16x8*)(wp + (((chunk * COUT + nBase + nt * 16 + m)) << 5) + quad * 8);
    };
    auto domfma = [&](bf16x8* av, bf16x8* bv) {
        #pragma unroll
        for (int g = 0; g < G; ++g)
            #pragma unroll
            for (int nt = 0; nt < NT; ++nt)
                acc[g][nt] = __builtin_amdgcn_mfma_f32_16x16x32_bf16(av[g], bv[nt], acc[g][nt], 0, 0, 0);
    };

    bf16x8 av[G], bA[NT], bB[NT];
    loadB(0, bA);
    #pragma unroll
    for (int it = 0; it < NIT; it += 2) {
        loadB(it + 1, bB);
        loadA(it, av);
        domfma(av, bA);
        if (it + 2 < NIT) loadB(it + 2, bA);
        loadA(it + 1, av);
        domfma(av, bB);
    }

    #pragma unroll
    for (int g = 0; g < G; ++g) {
        size_t rowbase = ((size_t)(b * (FIN / 2) + f2base + g)) * K;
        #pragma unroll
        for (int nt = 0; nt < NT; ++nt) {
            int col = nBase + nt * 16 + m;
            #pragma unroll
            for (int i = 0; i < 4; ++i) {
                int row = quad * 4 + i;
                if (row < K)
                    hout[(rowbase + row) * COUT + col] = f2bf(fmaxf(acc[g][nt][i], 0.f));
            }
        }
    }
}

// ---- conv3 + fused conv4 (round-11, VERBATIM — 169us, 84 VGPR, no spill) ----
template<int CIN, int COUT, int FIN, int MINW>
__launch_bounds__(256, MINW)
__global__ void conv_mfma_fused(const unsigned short* __restrict__ hin,
                                const unsigned short* __restrict__ wp,
                                const float* __restrict__ tb,
                                const unsigned short* __restrict__ zero16,
                                const float* __restrict__ w4,
                                float* __restrict__ pb) {
    constexpr int G = 4;
    constexpr int CHW = CIN / 8;
    constexpr int LOGC = (CHW == 16) ? 4 : 3;
    constexpr int NT = COUT / 64;
    constexpr int CCS = CIN / 32;
    constexpr int NIT = 9 * CCS;
    __shared__ alignas(16) unsigned short lin[G * 3 * 16 * CIN];
    __shared__ float red[4][4][4][2];        // [wave][quad][i][j]

    const int b = blockIdx.y;
    const int f2base = blockIdx.x * G;
    const int t = threadIdx.x;

    {
        constexpr int TOT = G * 3 * 16 * CHW;
        #pragma unroll
        for (int i = t; i < TOT; i += 256) {
            int c8 = i & (CHW - 1);
            int row = i >> LOGC;
            int p = row & 15;
            int tile = row >> 4;
            int df = tile % 3, g = tile / 3;
            int kin = p - 1;
            int fi = 2 * (f2base + g) + df - 1;
            bool valid = (kin >= 0) & (kin < K) & (fi >= 0);
            const unsigned short* src = valid
                ? hin + (((size_t)(b * FIN + fi)) * K + kin) * CIN + ((c8 ^ (p & 7)) << 3)
                : zero16;
            gl_lds16(src, &lin[i * 8]);
        }
    }
    __syncthreads();

    const int lane = t & 63;
    const int wave = t >> 6;
    const int m = lane & 15;
    const int quad = lane >> 4;
    const int nBase = wave * (COUT / 4);

    f32x4 acc[G][NT];
    #pragma unroll
    for (int nt = 0; nt < NT; ++nt) {
        float bias = tb[nBase + nt * 16 + m];
        #pragma unroll
        for (int g = 0; g < G; ++g)
            acc[g][nt] = f32x4{bias, bias, bias, bias};
    }

    auto loadA = [&](int it, bf16x8* av) {
        int df = it / (3 * CCS), dk = (it / CCS) % 3, cc = it % CCS;
        int p = m + dk; p = (p > 15) ? 15 : p;
        int cidx = (((cc * 4 + quad) ^ (p & 7)) << 3);
        #pragma unroll
        for (int g = 0; g < G; ++g)
            av[g] = *(const bf16x8*)&lin[((g * 3 + df) * 16 + p) * CIN + cidx];
    };
    auto loadB = [&](int it, bf16x8* bv) {
        int df = it / (3 * CCS), dk = (it / CCS) % 3, cc = it % CCS;
        int chunk = (df * 3 + dk) * CCS + cc;
        #pragma unroll
        for (int nt = 0; nt < NT; ++nt)
            bv[nt] = *(const bf16x8*)(wp + (((chunk * COUT + nBase + nt * 16 + m)) << 5) + quad * 8);
    };
    auto domfma = [&](bf16x8* av, bf16x8* bv) {
        #pragma unroll
        for (int g = 0; g < G; ++g)
            #pragma unroll
            for (int nt = 0; nt < NT; ++nt)
                acc[g][nt] = __builtin_amdgcn_mfma_f32_16x16x32_bf16(av[g], bv[nt], acc[g][nt], 0, 0, 0);
    };

    bf16x8 av[G], bA[NT], bB[NT];
    loadB(0, bA);
    #pragma unroll
    for (int it = 0; it < NIT; it += 2) {
        loadB(it + 1, bB);
        loadA(it, av);
        domfma(av, bA);
        if (it + 2 < NIT) loadB(it + 2, bA);
        loadA(it + 1, av);
        domfma(av, bB);
    }

    // ---- fused conv4 epilogue ----
    float part[4][2];
    #pragma unroll
    for (int i = 0; i < 4; ++i) { part[i][0] = 0.f; part[i][1] = 0.f; }
    #pragma unroll
    for (int g = 0; g < G; ++g) {
        int f = f2base + g;
        #pragma unroll
        for (int nt = 0; nt < NT; ++nt) {
            int c = nBase + nt * 16 + m;
            float w0 = w4[(0 * COUT + c) * F3 + f];
            float w1 = w4[(1 * COUT + c) * F3 + f];
            #pragma unroll
            for (int i = 0; i < 4; ++i) {
                float v = fmaxf(acc[g][nt][i], 0.f);
                part[i][0] = fmaf(v, w0, part[i][0]);
                part[i][1] = fmaf(v, w1, part[i][1]);
            }
        }
    }
    if (quad == 3) { part[2][0] = 0.f; part[2][1] = 0.f; part[3][0] = 0.f; part[3][1] = 0.f; }
    #pragma unroll
    for (int i = 0; i < 4; ++i)
        #pragma unroll
        for (int j = 0; j < 2; ++j) {
            float v = part[i][j];
            v += __shfl_xor(v, 1, 64);
            v += __shfl_xor(v, 2, 64);
            v += __shfl_xor(v, 4, 64);
            v += __shfl_xor(v, 8, 64);
            part[i][j] = v;
        }
    if (m == 0) {
        #pragma unroll
        for (int i = 0; i < 4; ++i) {
            red[wave][quad][i][0] = part[i][0];
            red[wave][quad][i][1] = part[i][1];
        }
    }
    __syncthreads();
    if (t < 2 * K) {
        int k = t >> 1, j = t & 1;
        float s = red[0][k >> 2][k & 3][j] + red[1][k >> 2][k & 3][j]
                + red[2][k >> 2][k & 3][j] + red[3][k >> 2][k & 3][j];
        pb[((size_t)b * 2 + blockIdx.x) * (2 * K) + t] = s;
    }
}

// ---- final: out[b,k,j] = pb[b][0][...] + pb[b][1][...] ----
__global__ void fin_kernel(const float* __restrict__ pb, float* __restrict__ out) {
    int idx = blockIdx.x * 256 + threadIdx.x;
    if (idx < B * 2 * K) {
        int b = idx / (2 * K), r = idx % (2 * K);
        out[idx] = pb[(size_t)b * (4 * K) + r] + pb[(size_t)b * (4 * K) + 2 * K + r];
    }
}

extern "C" void kernel_launch(void* const* d_in, const int* in_sizes, int n_in,
                              void* d_out, int out_size, void* d_ws, size_t ws_size,
                              hipStream_t stream) {
    const float* x   = (const float*)d_in[0];
    const float* sig = (const float*)d_in[1];
    const float* w1  = (const float*)d_in[2];
    const float* w2  = (const float*)d_in[3];
    const float* w3  = (const float*)d_in[4];
    const float* w4  = (const float*)d_in[5];
    const float* g1  = (const float*)d_in[6];
    const float* b1  = (const float*)d_in[7];
    const float* m1  = (const float*)d_in[8];
    const float* v1  = (const float*)d_in[9];
    const float* g2  = (const float*)d_in[10];
    const float* b2  = (const float*)d_in[11];
    const float* m2  = (const float*)d_in[12];
    const float* v2  = (const float*)d_in[13];
    const float* g3  = (const float*)d_in[14];
    const float* b3  = (const float*)d_in[15];
    const float* m3  = (const float*)d_in[16];
    const float* v3  = (const float*)d_in[17];

    char* ws = (char*)d_ws;
    size_t off = 0;
    auto alloc = [&](size_t bytes) {
        char* p = ws + off;
        off += (bytes + 255) & ~(size_t)255;
        return p;
    };
    unsigned short* h1  = (unsigned short*)alloc((size_t)B * F1 * K * C1 * 2);
    unsigned short* h2  = (unsigned short*)alloc((size_t)B * F2 * K * C2 * 2);
    float* w1f = (float*)alloc((size_t)C1 * 2 * 9 * 4);
    float* t1  = (float*)alloc((size_t)C1 * 4);
    unsigned short* wp2 = (unsigned short*)alloc((size_t)9 * C1 * C2 * 2);
    float* t2  = (float*)alloc((size_t)C2 * 4);
    unsigned short* wp3 = (unsigned short*)alloc((size_t)9 * C2 * C3 * 2);
    float* t3  = (float*)alloc((size_t)C3 * 4);
    float* zbuf = (float*)alloc(16);
    float* pb   = (float*)alloc((size_t)B * 2 * 2 * K * 4);   // per-block conv4 partials

    repack_w1<<<(C1 * 2 * 9 + 255) / 256, 256, 0, stream>>>(w1, g1, b1, m1, v1, w1f, t1, zbuf);
    repack_mfma<C1, C2><<<(9 * C1 * C2 + 255) / 256, 256, 0, stream>>>(w2, g2, b2, m2, v2, wp2, t2);
    repack_mfma<C2, C3><<<(9 * C2 * C3 + 255) / 256, 256, 0, stream>>>(w3, g3, b3, m3, v3, wp3, t3);

    conv1_kernel<<<B, 256, 0, stream>>>(x, sig, w1f, t1, h1);
    // conv2: round-2 structure, G=4 -> grid (4, B)
    conv_mfma<C1, C2, F1, 4><<<dim3(F1 / 2 / 4, B), 256, 0, stream>>>(h1, wp2, t2, (const unsigned short*)zbuf, h2);
    // conv3 + fused conv4: grid (2, B); writes 28-float partials per block
    conv_mfma_fused<C2, C3, F2, 3><<<dim3(F2 / 2 / 4, B), 256, 0, stream>>>(h2, wp3, t3, (const unsigned short*)zbuf, w4, pb);
    fin_kernel<<<(B * 2 * K + 255) / 256, 256, 0, stream>>>(pb, (float*)d_out);
}